// Round 8
// baseline (408.735 us; speedup 1.0000x reference)
//
#include <hip/hip_runtime.h>
#include <hip/hip_bf16.h>

#define B_ROWS 256
#define S_SUP  65536
#define D_DIM  768
#define QSZ    512
#define NCH    24          // 768 / 32 k-chunks
#define ACH    8192        // A chunk: 4 planes * 128 rows * 16 B (bf16 image)
#define APANEL 196608      // bytes per 128-row A panel (24 chunks * 8 KB)

typedef short bf16x8 __attribute__((ext_vector_type(8)));
typedef float f32x4  __attribute__((ext_vector_type(4)));
typedef float f32x16 __attribute__((ext_vector_type(16)));

__device__ __forceinline__ bf16x8 cvt8(float4 a, float4 b) {
  bf16x8 r;
  r[0] = (short)(__float_as_uint(a.x) >> 16);
  r[1] = (short)(__float_as_uint(a.y) >> 16);
  r[2] = (short)(__float_as_uint(a.z) >> 16);
  r[3] = (short)(__float_as_uint(a.w) >> 16);
  r[4] = (short)(__float_as_uint(b.x) >> 16);
  r[5] = (short)(__float_as_uint(b.y) >> 16);
  r[6] = (short)(__float_as_uint(b.z) >> 16);
  r[7] = (short)(__float_as_uint(b.w) >> 16);
  return r;
}

__device__ __forceinline__ void gl_lds16(const void* g, void* l) {
  __builtin_amdgcn_global_load_lds(
      (const __attribute__((address_space(1))) unsigned int*)g,
      (__attribute__((address_space(3))) unsigned int*)l, 16, 0, 0);
}

// block-wide sum (float), result broadcast to all 256 threads (4 waves)
__device__ __forceinline__ float block_sum(float v) {
  __shared__ float tmp[4];
  #pragma unroll
  for (int m = 32; m >= 1; m >>= 1) v += __shfl_xor(v, m, 64);
  __syncthreads();
  if ((threadIdx.x & 63) == 0) tmp[threadIdx.x >> 6] = v;
  __syncthreads();
  return tmp[0] + tmp[1] + tmp[2] + tmp[3];
}

__device__ __forceinline__ double block_sum_d(double v) {
  __shared__ double tmp[4];
  #pragma unroll
  for (int m = 32; m >= 1; m >>= 1) v += __shfl_xor(v, m, 64);
  __syncthreads();
  if ((threadIdx.x & 63) == 0) tmp[threadIdx.x >> 6] = v;
  __syncthreads();
  return tmp[0] + tmp[1] + tmp[2] + tmp[3];
}

// ---- kernel 0: zero accumulators ----
__global__ __launch_bounds__(256) void init_kernel(unsigned long long* gmax, double* bden) {
  int t = threadIdx.x;
  gmax[t] = 0ull;
  for (int i = t; i < 3 * B_ROWS; i += 256) bden[i] = 0.0;
}

// ---- kernel 1: augs[j-1] = normalize(V[j]*L); j==0 -> org_bf16 image ----
// A image: [rp][c][g][r][e]: ushort idx = (((rp*24 + c)*4 + g)*128 + r)*8 + e
// rp = row panel (b>>7), r = b&127; c = k>>5, g = (k>>3)&3, e = k&7.
// Chunk (rp,c) is an 8 KB block = the LDS image (verbatim gl_lds copy).
__global__ __launch_bounds__(256) void prep_kernel(const float* __restrict__ V,
                                                   const float* __restrict__ L,
                                                   unsigned short* __restrict__ orgb,
                                                   float* __restrict__ augs) {
  int jb = blockIdx.x;            // 0..1023
  int j = jb >> 8, b = jb & 255;
  int tid = threadIdx.x;
  __shared__ float srow[D_DIM];
  const float* v = V + ((size_t)j * B_ROWS + b) * D_DIM;
  const float* l = L + (size_t)b * D_DIM;
  float p[3]; float ssq = 0.f;
  #pragma unroll
  for (int i = 0; i < 3; ++i) {
    int k = tid + 256 * i;
    p[i] = v[k] * l[k];
    ssq += p[i] * p[i];
  }
  ssq = block_sum(ssq);
  float inv = 1.0f / fmaxf(sqrtf(ssq), 1e-12f);
  if (j == 0) {
    #pragma unroll
    for (int i = 0; i < 3; ++i) srow[tid + 256 * i] = p[i] * inv;
    __syncthreads();
    if (tid < 96) {                       // k-group tid: k0 = 8*tid
      int k0 = tid * 8;
      float4 f0 = *(const float4*)&srow[k0];
      float4 f1 = *(const float4*)&srow[k0 + 4];
      bf16x8 hv = cvt8(f0, f1);
      int rp = b >> 7, r = b & 127;
      int c = k0 >> 5, g = (k0 >> 3) & 3;
      *(bf16x8*)(orgb + ((((size_t)rp * 24 + c) * 4 + g) * 128 + r) * 8) = hv;
    }
  } else {
    float* dst = augs + ((size_t)(j - 1) * B_ROWS + b) * D_DIM;
    #pragma unroll
    for (int i = 0; i < 3; ++i) dst[tid + 256 * i] = p[i] * inv;
  }
}

// ---- kernel 2: sim = org @ sf^T (bf16 MFMA 32x32x16), per-row argmax ----
// m97-structure: SMALL blocks, MANY per CU. 256 thr = 4 waves, tile 128x128,
// BK=32, LDS 16 KB, plain __syncthreads (2 per chunk). __launch_bounds__(256,4)
// -> VGPR<=128 -> 16 waves/CU = 4 independent blocks/CU covering each other's
// barrier drains (m97/m114 mechanism). Grid 1024 all-resident; block pairs
// (2cp,2cp+1) share the B panel -> second read hits L2/L3.
__global__ __launch_bounds__(256, 4) void sim_argmax_kernel(const unsigned short* __restrict__ orgb,
                                                            const float* __restrict__ sf,
                                                            unsigned long long* __restrict__ gmax) {
  const int tid = threadIdx.x;
  const int w   = tid >> 6;           // wave 0..3
  const int l   = tid & 63;
  const int h   = l >> 5;             // half 0/1 (k-slice select)
  const int c31 = l & 31;
  const int wr  = w & 1;              // row band (64)
  const int wc  = w >> 1;             // col band (64)
  const int rp  = blockIdx.x & 1;     // row panel: pairs share B panel
  const int cp  = blockIdx.x >> 1;
  const int s0  = cp * 128;

  __shared__ __align__(16) char smem[16384];   // A 8K | B 8K

  f32x16 acc[4];                      // rt*2+nt
  #pragma unroll
  for (int t = 0; t < 4; ++t)
    #pragma unroll
    for (int r = 0; r < 16; ++r) acc[t][r] = 0.f;

  // A staging: verbatim 8 KB copy, 2 x gl_lds16 per thread
  const char* agb = (const char*)orgb + (size_t)rp * APANEL + tid * 16;
  char* adst = smem + tid * 16;

  // B staging: thread -> col bcol = tid>>1, k-half kh = tid&1 (16 k = 64 B)
  const int bcol = tid >> 1;
  const int kh   = tid & 1;
  const float* bsrc = sf + (size_t)(s0 + bcol) * D_DIM + kh * 16;
  const int g0 = kh * 2;
  char* bw0 = smem + 8192 + g0 * 2048 + (((bcol ^ g0) & 127) << 4);
  char* bw1 = smem + 8192 + (g0 + 1) * 2048 + (((bcol ^ (g0 + 1)) & 127) << 4);

  // read-side constants
  const int arow = (wr * 64 + c31) * 16;     // + 512 for rt=1 (rows +32)
  const int bc0  = wc * 64 + c31;
  const int bc1  = bc0 + 32;

  for (int c = 0; c < NCH; ++c) {
    // stage A (gl_lds, async) + B (reg -> cvt -> LDS, XOR swizzle)
    {
      const char* g = agb + c * ACH;
      gl_lds16(g,        adst);
      gl_lds16(g + 4096, adst + 4096);
    }
    {
      const float4* bp = (const float4*)(bsrc + c * 32);
      float4 f0 = bp[0], f1 = bp[1], f2 = bp[2], f3 = bp[3];
      *(bf16x8*)bw0 = cvt8(f0, f1);
      *(bf16x8*)bw1 = cvt8(f2, f3);
    }
    __syncthreads();

    #pragma unroll
    for (int ks = 0; ks < 2; ++ks) {
      const int g = ks * 2 + h;
      bf16x8 a0 = *(const bf16x8*)(smem + g * 2048 + arow);
      bf16x8 a1 = *(const bf16x8*)(smem + g * 2048 + arow + 512);
      bf16x8 b0 = *(const bf16x8*)(smem + 8192 + g * 2048 + (((bc0 ^ g) & 127) << 4));
      bf16x8 b1 = *(const bf16x8*)(smem + 8192 + g * 2048 + (((bc1 ^ g) & 127) << 4));
      acc[0] = __builtin_amdgcn_mfma_f32_32x32x16_bf16(a0, b0, acc[0], 0, 0, 0);
      acc[1] = __builtin_amdgcn_mfma_f32_32x32x16_bf16(a0, b1, acc[1], 0, 0, 0);
      acc[2] = __builtin_amdgcn_mfma_f32_32x32x16_bf16(a1, b0, acc[2], 0, 0, 0);
      acc[3] = __builtin_amdgcn_mfma_f32_32x32x16_bf16(a1, b1, acc[3], 0, 0, 0);
    }
    __syncthreads();
  }

  // ---- epilogue: per-row argmax over this block's 128 cols ----
  float* smax = (float*)smem;            // [2 wc][128 rows]
  int*   sidx = (int*)(smem + 2048);
  #pragma unroll
  for (int rt = 0; rt < 2; ++rt) {
    #pragma unroll
    for (int rg = 0; rg < 16; ++rg) {
      float v0 = acc[rt * 2 + 0][rg];
      float v1 = acc[rt * 2 + 1][rg];
      int i0 = s0 + bc0;
      int i1 = s0 + bc1;
      float v; int idx;
      if (v1 > v0) { v = v1; idx = i1; } else { v = v0; idx = i0; }
      #pragma unroll
      for (int m = 1; m < 32; m <<= 1) {   // reduce 32 col-lanes (stays in half)
        float ov = __shfl_xor(v, m, 64);
        int   oi = __shfl_xor(idx, m, 64);
        if (ov > v || (ov == v && oi < idx)) { v = ov; idx = oi; }
      }
      if (c31 == 0) {
        int row = wr * 64 + rt * 32 + (rg & 3) + 8 * (rg >> 2) + 4 * h;  // m74/m101
        smax[wc * 128 + row] = v;
        sidx[wc * 128 + row] = idx;
      }
    }
  }
  __syncthreads();
  if (tid < 128) {
    int row = tid;
    float v  = smax[row];       int idx = sidx[row];
    float ov = smax[128 + row]; int oi  = sidx[128 + row];
    if (ov > v || (ov == v && oi < idx)) { v = ov; idx = oi; }
    unsigned u = __float_as_uint(v);
    unsigned key = (u & 0x80000000u) ? ~u : (u | 0x80000000u);
    unsigned long long packed = ((unsigned long long)key << 32) |
                                (unsigned long long)(0xFFFFFFFFu - (unsigned)idx);
    int b = rp * 128 + row;
    if (packed > gmax[b]) atomicMax(gmax + b, packed);   // stale read safe
  }
}

// ---- kernel 3: nn = normalize(sf[nn_idx]); nnT; num = dot(nn, augs[0][b]) / T ----
__global__ __launch_bounds__(256) void nn_kernel(const unsigned long long* __restrict__ gmax,
                                                 const float* __restrict__ sf,
                                                 const float* __restrict__ augs,
                                                 float* __restrict__ nn,
                                                 float* __restrict__ nnT,
                                                 float* __restrict__ num) {
  int b = blockIdx.x, tid = threadIdx.x;
  int idx = (int)(0xFFFFFFFFu - (unsigned)(gmax[b] & 0xFFFFFFFFull));
  const float* row = sf + (size_t)idx * D_DIM;
  float p[3]; float ssq = 0.f;
  #pragma unroll
  for (int i = 0; i < 3; ++i) { p[i] = row[tid + 256 * i]; ssq += p[i] * p[i]; }
  ssq = block_sum(ssq);
  float inv = 1.0f / fmaxf(sqrtf(ssq), 1e-12f);
  const float* a0 = augs + (size_t)b * D_DIM;    // augs[0][b]
  float dot = 0.f;
  #pragma unroll
  for (int i = 0; i < 3; ++i) {
    int k = tid + 256 * i;
    float nv = p[i] * inv;
    nn[(size_t)b * D_DIM + k] = nv;
    nnT[(size_t)k * B_ROWS + b] = nv;
    dot += nv * a0[k];
  }
  dot = block_sum(dot);
  if (tid == 0) num[b] = dot * 10.0f;            // 1/TEMP = 10
}

// ---- kernel 4: batch_den[j][b] += sum_i exp(10*dot(nn_b, aug_ji)) (double acc) ----
__global__ __launch_bounds__(256) void bden_kernel(const float* __restrict__ augs,
                                                   const float* __restrict__ nnT,
                                                   double* __restrict__ bden) {
  int jc = blockIdx.x;                 // 0..191
  int j = jc >> 6, c = jc & 63;
  int i0 = c * 4;
  __shared__ float s_aug[4 * D_DIM];
  const float* src = augs + ((size_t)j * B_ROWS + i0) * D_DIM;
  for (int idx = threadIdx.x; idx < 4 * D_DIM; idx += 256) s_aug[idx] = src[idx];
  __syncthreads();
  int b = threadIdx.x;
  float a0 = 0.f, a1 = 0.f, a2 = 0.f, a3 = 0.f;
  for (int k = 0; k < D_DIM; ++k) {
    float nv = nnT[(size_t)k * B_ROWS + b];
    a0 += nv * s_aug[k];
    a1 += nv * s_aug[D_DIM + k];
    a2 += nv * s_aug[2 * D_DIM + k];
    a3 += nv * s_aug[3 * D_DIM + k];
  }
  double v = exp((double)a0 * 10.0) + exp((double)a1 * 10.0) +
             exp((double)a2 * 10.0) + exp((double)a3 * 10.0);
  atomicAdd(&bden[j * B_ROWS + b], v);
}

// ---- kernel 5: GPS-filtered queue denominator (16 lanes per row, double exp-sum) ----
__global__ __launch_bounds__(256) void queue_kernel(const float* __restrict__ gps,
                                                    const float* __restrict__ sgps,
                                                    const float* __restrict__ sf,
                                                    const float* __restrict__ nn,
                                                    double* __restrict__ qden) {
  int b = blockIdx.x, tid = threadIdx.x;
  int w = tid >> 6, lane = tid & 63;
  __shared__ int qidx[QSZ];
  __shared__ int s_count;
  __shared__ int s_wcnt[4];
  __shared__ __align__(16) float s_nn[D_DIM];
  __shared__ double s_gsum[16];
  for (int k = tid; k < D_DIM; k += 256) s_nn[k] = nn[(size_t)b * D_DIM + k];
  if (tid == 0) s_count = 0;
  __syncthreads();

  const float r = 0.017453292519943295f;
  float lat1 = gps[b * 2 + 0] * r, lon1 = gps[b * 2 + 1] * r;
  float cl1 = cosf(lat1);
  int base = 0;
  while (true) {
    int count = s_count;
    if (count >= QSZ || base >= S_SUP) break;
    int s = base + tid;
    float lat2 = sgps[s * 2 + 0] * r, lon2 = sgps[s * 2 + 1] * r;
    float sdlat = sinf((lat2 - lat1) * 0.5f);
    float sdlon = sinf((lon2 - lon1) * 0.5f);
    float a = sdlat * sdlat + cl1 * cosf(lat2) * sdlon * sdlon;
    a = fminf(fmaxf(a, 0.f), 1.f);
    float d = 2.0f * 6371.0088f * asinf(sqrtf(a));
    bool valid = d > 25.0f;

    unsigned long long m = __ballot(valid);
    int wcnt = __popcll(m);
    if (lane == 0) s_wcnt[w] = wcnt;
    __syncthreads();
    int wbase = count;
    for (int i = 0; i < w; ++i) wbase += s_wcnt[i];
    int pos = wbase + __popcll(m & ((1ull << lane) - 1ull));
    if (valid && pos < QSZ) qidx[pos] = s;
    __syncthreads();
    if (tid == 0) {
      int total = s_wcnt[0] + s_wcnt[1] + s_wcnt[2] + s_wcnt[3];
      s_count = min(QSZ, count + total);
    }
    base += 256;
    __syncthreads();
  }
  int count = s_count;

  // phase 2: 16 lanes per row, 16 rows in flight per block
  int g  = lane >> 4;                  // group 0..3 within wave
  int l2 = lane & 15;
  double acc = 0.0;
  const float4* nn4 = (const float4*)s_nn;
  for (int q = w * 4 + g; q < count; q += 16) {
    const float4* row = (const float4*)(sf + (size_t)qidx[q] * D_DIM);
    float dot = 0.f;
    #pragma unroll
    for (int i = 0; i < 12; ++i) {
      float4 a = row[l2 + 16 * i];
      float4 nv = nn4[l2 + 16 * i];
      dot += a.x * nv.x + a.y * nv.y + a.z * nv.z + a.w * nv.w;
    }
    #pragma unroll
    for (int m2 = 8; m2 >= 1; m2 >>= 1) dot += __shfl_xor(dot, m2, 16);
    if (l2 == 0) acc += exp((double)dot * 10.0);
  }
  if (l2 == 0) s_gsum[w * 4 + g] = acc;
  __syncthreads();
  if (tid == 0) {
    double t = (double)(QSZ - count);
    #pragma unroll
    for (int i = 0; i < 16; ++i) t += s_gsum[i];
    qden[b] = t;
  }
}

// ---- kernel 6: final scalar loss (double) ----
__global__ __launch_bounds__(256) void loss_kernel(const float* __restrict__ num,
                                                   const double* __restrict__ bden,
                                                   const double* __restrict__ qden,
                                                   float* __restrict__ out) {
  int b = threadIdx.x;
  double q = qden[b];
  double n = (double)num[b];
  double t = 0.0;
  #pragma unroll
  for (int j = 0; j < 3; ++j) t += n - log(bden[j * B_ROWS + b] + q);
  t = block_sum_d(t);
  if (b == 0) out[0] = (float)(-t / 256.0);
}

extern "C" void kernel_launch(void* const* d_in, const int* in_sizes, int n_in,
                              void* d_out, int out_size, void* d_ws, size_t ws_size,
                              hipStream_t stream) {
  const float* V    = (const float*)d_in[0];   // (4,256,768)
  const float* L    = (const float*)d_in[1];   // (256,768)
  const float* gps  = (const float*)d_in[2];   // (256,2)
  const float* sf   = (const float*)d_in[3];   // (65536,768)
  const float* sgps = (const float*)d_in[4];   // (65536,2)
  float* out = (float*)d_out;

  char* ws = (char*)d_ws;
  size_t off = 0;
  unsigned short* orgb = (unsigned short*)(ws + off); off += 393216;  // 2 panels * 24 * 8 KB
  float* augs = (float*)(ws + off); off += 2359296;                   // 3*256*768*4
  float* nn   = (float*)(ws + off); off += 786432;
  float* nnT  = (float*)(ws + off); off += 786432;
  float* num  = (float*)(ws + off); off += 1024;                      // 256*4
  double* bden = (double*)(ws + off); off += 6144;                    // 3*256*8
  double* qden = (double*)(ws + off); off += 2048;                    // 256*8
  unsigned long long* gmax = (unsigned long long*)(ws + off); off += 2048;

  init_kernel<<<1, 256, 0, stream>>>(gmax, bden);
  prep_kernel<<<1024, 256, 0, stream>>>(V, L, orgb, augs);
  sim_argmax_kernel<<<(S_SUP / 128) * 2, 256, 0, stream>>>(orgb, sf, gmax);
  nn_kernel<<<B_ROWS, 256, 0, stream>>>(gmax, sf, augs, nn, nnT, num);
  bden_kernel<<<192, 256, 0, stream>>>(augs, nnT, bden);
  queue_kernel<<<B_ROWS, 256, 0, stream>>>(gps, sgps, sf, nn, qden);
  loss_kernel<<<1, 256, 0, stream>>>(num, bden, qden, out);
}